// Round 5
// baseline (658.487 us; speedup 1.0000x reference)
//
#include <hip/hip_runtime.h>
#include <hip/hip_bf16.h>

// ---------------------------------------------------------------------------
// Attention: out = softmax((q Wq^T + bq)(k Wk^T + bk)^T * inv_sqrt_d * mask) (v Wv^T + bv)
// B=8, T=2048, D=512.  fp32 I/O; bf16 MFMA, fp32 accum.
//
// ws layout (50,331,648 B, all LINEAR — swizzles live in DMA source addresses):
//   qp  [16384][512] bf16
//   kp  [16384][512] bf16
//   vpT [b][kt=64][d=512][32] bf16
// ---------------------------------------------------------------------------

typedef __attribute__((ext_vector_type(4))) float  f32x4;
typedef __attribute__((ext_vector_type(8))) short  s16x8;
typedef __attribute__((ext_vector_type(8))) __bf16 bf16x8;

#define AS1 __attribute__((address_space(1)))
#define AS3 __attribute__((address_space(3)))

__device__ __forceinline__ f32x4 mfma16(s16x8 a, s16x8 b, f32x4 c) {
  return __builtin_amdgcn_mfma_f32_16x16x32_bf16(
      __builtin_bit_cast(bf16x8, a), __builtin_bit_cast(bf16x8, b), c, 0, 0, 0);
}

__device__ __forceinline__ unsigned short f2bf(float f) {
  unsigned u = __float_as_uint(f);
  return (unsigned short)((u + 0x7fffu + ((u >> 16) & 1u)) >> 16);
}

__device__ __forceinline__ s16x8 pack8(f32x4 a, f32x4 b) {
  union { s16x8 v; unsigned int u[4]; } r;
  __hip_bfloat162 t0 = __float22bfloat162_rn(make_float2(a[0], a[1]));
  __hip_bfloat162 t1 = __float22bfloat162_rn(make_float2(a[2], a[3]));
  __hip_bfloat162 t2 = __float22bfloat162_rn(make_float2(b[0], b[1]));
  __hip_bfloat162 t3 = __float22bfloat162_rn(make_float2(b[2], b[3]));
  __builtin_memcpy(&r.u[0], &t0, 4);
  __builtin_memcpy(&r.u[1], &t1, 4);
  __builtin_memcpy(&r.u[2], &t2, 4);
  __builtin_memcpy(&r.u[3], &t3, 4);
  return r.v;
}

__device__ __forceinline__ void gld16(const unsigned short* g, unsigned short* l) {
  __builtin_amdgcn_global_load_lds((const AS1 unsigned int*)g,
                                   (AS3 unsigned int*)l, 16, 0, 0);
}
__device__ __forceinline__ void gldf(const float* g, float* l) {
  __builtin_amdgcn_global_load_lds((const AS1 unsigned int*)g,
                                   (AS3 unsigned int*)l, 16, 0, 0);
}

#define SCALE 0.044194173824159216f  // 1/sqrt(512)

// ---------------------------------------------------------------------------
// Projection GEMM (unchanged).
// ---------------------------------------------------------------------------
__global__ __launch_bounds__(256, 2) void proj_kernel(
    const float* __restrict__ q,  const float* __restrict__ kk, const float* __restrict__ v,
    const float* __restrict__ Wq, const float* __restrict__ bq,
    const float* __restrict__ Wk, const float* __restrict__ bk,
    const float* __restrict__ Wv, const float* __restrict__ bv,
    unsigned short* __restrict__ qp, unsigned short* __restrict__ kp,
    unsigned short* __restrict__ vpT)
{
  const int id = blockIdx.x;
  const int c  = id & 7;
  const int j  = id >> 3;
  const int z  = j >> 6;
  const int j2 = j & 63;
  int xt, yt;
  if (z < 2) { yt = j2 & 3; xt = (j2 >> 2) * 8 + c; }
  else       { xt = j2 & 3; yt = (j2 >> 2) * 8 + c; }

  const float* Asrc; const float* Bsrc; const float* bias;
  if (z == 0)      { Asrc = q;  Bsrc = Wq; bias = bq; }
  else if (z == 1) { Asrc = kk; Bsrc = Wk; bias = bk; }
  else             { Asrc = Wv; Bsrc = v;  bias = bv; }
  const int Arow0 = xt * 128, Brow0 = yt * 128;
  const float* Ag = Asrc + (size_t)Arow0 * 512;
  const float* Bg = Bsrc + (size_t)Brow0 * 512;

  __shared__ __align__(16) float Abuf[2][128 * 32];
  __shared__ __align__(16) float Bbuf[2][128 * 32];

  const int tid  = threadIdx.x;
  const int lane = tid & 63;
  const int w    = tid >> 6;
  const int wr   = w >> 1, wc = w & 1;
  const int m    = lane & 15;
  const int quad = lane >> 4;

  const int lr = lane >> 3;
  const int sw = ((lane & 7) ^ lr) * 4;

  f32x4 acc[4][4];
  #pragma unroll
  for (int i = 0; i < 4; i++)
    #pragma unroll
    for (int n = 0; n < 4; n++) acc[i][n] = (f32x4){0.f, 0.f, 0.f, 0.f};

  #pragma unroll
  for (int i = 0; i < 4; i++) {
    int r0 = w * 32 + i * 8;
    gldf(Ag + (size_t)(r0 + lr) * 512 + sw, &Abuf[0][r0 * 32]);
  }
  #pragma unroll
  for (int i = 0; i < 4; i++) {
    int r0 = w * 32 + i * 8;
    gldf(Bg + (size_t)(r0 + lr) * 512 + sw, &Bbuf[0][r0 * 32]);
  }

  const int xrow = m & 7;

  #pragma unroll 1
  for (int kc = 0; kc < 16; kc++) {
    const int cur = kc & 1;
    asm volatile("s_barrier" ::: "memory");
    if (kc < 15) {
      const int nxt = cur ^ 1;
      const size_t ko = (size_t)(kc + 1) * 32;
      #pragma unroll
      for (int i = 0; i < 4; i++) {
        int r0 = w * 32 + i * 8;
        gldf(Ag + (size_t)(r0 + lr) * 512 + ko + sw, &Abuf[nxt][r0 * 32]);
      }
      #pragma unroll
      for (int i = 0; i < 4; i++) {
        int r0 = w * 32 + i * 8;
        gldf(Bg + (size_t)(r0 + lr) * 512 + ko + sw, &Bbuf[nxt][r0 * 32]);
      }
      asm volatile("s_waitcnt vmcnt(8)" ::: "memory");
    } else {
      asm volatile("s_waitcnt vmcnt(0)" ::: "memory");
    }
    asm volatile("s_barrier" ::: "memory");

    const float* Ac = &Abuf[cur][0];
    const float* Bc = &Bbuf[cur][0];
    s16x8 af[4], bf[4];
    #pragma unroll
    for (int mt = 0; mt < 4; mt++) {
      int row = wr * 64 + mt * 16 + m;
      int p0 = ((quad * 2) ^ xrow) * 4, p1 = ((quad * 2 + 1) ^ xrow) * 4;
      f32x4 a = *(const f32x4*)(Ac + row * 32 + p0);
      f32x4 b = *(const f32x4*)(Ac + row * 32 + p1);
      af[mt] = pack8(a, b);
    }
    #pragma unroll
    for (int nt = 0; nt < 4; nt++) {
      int row = wc * 64 + nt * 16 + m;
      int p0 = ((quad * 2) ^ xrow) * 4, p1 = ((quad * 2 + 1) ^ xrow) * 4;
      f32x4 a = *(const f32x4*)(Bc + row * 32 + p0);
      f32x4 b = *(const f32x4*)(Bc + row * 32 + p1);
      bf[nt] = pack8(a, b);
    }
    #pragma unroll
    for (int mt = 0; mt < 4; mt++)
      #pragma unroll
      for (int nt = 0; nt < 4; nt++)
        acc[mt][nt] = mfma16(af[mt], bf[nt], acc[mt][nt]);
  }

  if (z < 2) {
    unsigned short* o = (z == 0) ? qp : kp;
    #pragma unroll
    for (int nt = 0; nt < 4; nt++) {
      int   e_g = Brow0 + wc * 64 + nt * 16 + m;
      float bb  = bias[e_g];
      #pragma unroll
      for (int mt = 0; mt < 4; mt++) {
        #pragma unroll
        for (int r = 0; r < 4; r++) {
          int t_g = Arow0 + wr * 64 + mt * 16 + quad * 4 + r;
          o[(size_t)t_g * 512 + e_g] = f2bf(acc[mt][nt][r] + bb);
        }
      }
    }
  } else {
    #pragma unroll
    for (int mt = 0; mt < 4; mt++) {
      #pragma unroll
      for (int r = 0; r < 4; r++) {
        int   e_g = Arow0 + wr * 64 + mt * 16 + quad * 4 + r;
        float bb  = bias[e_g];
        #pragma unroll
        for (int nt = 0; nt < 4; nt++) {
          int t_g = Brow0 + wc * 64 + nt * 16 + m;
          int bbi = t_g >> 11, ti = t_g & 2047;
          int ktl = ti >> 5,   kq = ti & 31;
          vpT[(((size_t)bbi * 64 + ktl) * 512 + e_g) * 32 + kq] =
              f2bf(acc[mt][nt][r] + bb);
        }
      }
    }
  }
}

// ---------------------------------------------------------------------------
// Flash attention v6: 4-wave blocks (2 S + 2 PV), 32 q-rows, grid 512,
// 2 blocks/CU (LDS ~69 KB, <=256 unified regs/wave) -> two independent
// barrier groups per CU interleave and hide each other's stalls.
// S-waves (w<2): ksw=w key-half; 32 rows x 16 keys; stage ALL K (16 gld/iter,
//   rows w*16..w*16+15 == exactly the rows this wave reads back) + mask (8).
//   Drain vmcnt(24) retires mask(KT)+K(KT), leaves next window in flight.
// PV-waves (w>=2): dq=w&1 d-half; 32 rows x 256 cols, lag 1 iter; V frags
//   direct global->reg (vf[16], identity map from vpT layout), pure
//   compiler-tracked VMEM queue (no inline DMA) so auto-waitcnt is sound.
// Kbuf[2] ring (64 KB), Pbuf parity-dbuf (4.5 KB). 2 barriers/iter.
// ---------------------------------------------------------------------------
__global__ __launch_bounds__(256, 2) void flash_kernel(
    const unsigned short* __restrict__ qp, const unsigned short* __restrict__ kp,
    const unsigned short* __restrict__ vpT, const float* __restrict__ mask,
    float* __restrict__ out)
{
  const int id   = blockIdx.x;
  const int b    = id & 7;
  const int q0   = (id >> 3) * 32;
  const int tid  = threadIdx.x;
  const int lane = tid & 63;
  const int w    = tid >> 6;       // 0..3
  const int m    = lane & 15;
  const int quad = lane >> 4;
  const bool isS = (w < 2);
  const int ksw  = w & 1;          // S: key-half (16 keys)
  const int dq   = w & 1;          // PV: d-half (256 cols)

  __shared__ __align__(16) unsigned short Kbuf[2][32 * 512];  // 64 KB
  __shared__ __align__(16) unsigned short Pbuf[2][32 * 36];   // 4.5 KB
  __shared__ float LSf[2][32];

  const unsigned short* kgb   = kp  + (size_t)b * 2048 * 512;
  // per-lane V base: e=(dq*256 + dt*16 + m), kq=quad*8 -> +dt*512 shorts,
  // +16384 shorts per key-tile. 16B/lane contiguous per wave.
  const unsigned short* vlane = vpT + (size_t)b * 64 * 16384
                              + (size_t)(dq * 256 + m) * 32 + quad * 8;
  const float* mbase = mask + ((size_t)b * 2048 + q0 + quad * 4) * 2048
                     + ksw * 16 + m;

  // swizzled K-read offsets (same family as v5 — verified)
  const int oE   = ((quad ^ (m & 7)) & 7) * 8;
  const int oO   = (((quad ^ (m & 7)) ^ 4) & 7) * 8;
  const int krow = (ksw * 16 + m) * 512;

  f32x4 st[32];              // S: Q frags (bit-cast) | PV: O acc
  s16x8 vf[16];              // PV: V frags for current lagged tile
  float lsum[8] = {0.f, 0.f, 0.f, 0.f, 0.f, 0.f, 0.f, 0.f};
  float mvA[8], mvB[8];

  if (isS) {
    const unsigned short* qb = qp + ((size_t)b * 2048 + q0 + m) * 512;
    #pragma unroll
    for (int ks = 0; ks < 16; ks++) {
      s16x8 a0 = *(const s16x8*)(qb + ks * 32 + quad * 8);
      s16x8 a1 = *(const s16x8*)(qb + 16 * 512 + ks * 32 + quad * 8);
      st[ks]      = __builtin_bit_cast(f32x4, a0);
      st[16 + ks] = __builtin_bit_cast(f32x4, a1);
    }
    asm volatile("" ::: "memory");      // keep VMEM issue groups ordered
    // mask(0)
    #pragma unroll
    for (int t = 0; t < 2; t++)
      #pragma unroll
      for (int r = 0; r < 4; r++)
        mvA[t * 4 + r] = mbase[(size_t)(t * 16 + r) * 2048];
    asm volatile("" ::: "memory");
    // K(0): rows w*16 .. w*16+15 (self-consumed)
    #pragma unroll
    for (int i = 0; i < 16; i++) {
      int r = (w << 4) + i;
      gld16(kgb + (size_t)r * 512 + ((lane ^ (r & 7)) * 8), &Kbuf[0][r * 512]);
    }
  } else {
    #pragma unroll
    for (int i = 0; i < 32; i++) st[i] = (f32x4){0.f, 0.f, 0.f, 0.f};
  }
  asm volatile("s_waitcnt vmcnt(0)" ::: "memory");  // Q, K(0), mask(0) resident

// Per-wave VMEM queues (oldest -> newest), in-order retirement:
//   S : [mask(KT)8, K(KT)16] [mask(KT+1)8, K(KT+1)16] -> vmcnt(24) retires
//        mask(KT)+K(KT); K(KT) rows are this wave's own reads.
//   PV: [vf = V(KT-1)] only -> compiler auto-wait before first MFMA use.
#define FLASH_ITER(KT, MVU, MVL)                                               \
  {                                                                            \
    const int cur = (KT) & 1;                                                  \
    asm volatile("s_barrier" ::: "memory"); /* compute(KT-1) done all waves */ \
    if (isS) {                                                                 \
      if ((KT) + 1 < 64) {                                                     \
        _Pragma("unroll")                                                      \
        for (int t = 0; t < 2; t++)                                            \
          _Pragma("unroll")                                                    \
          for (int r = 0; r < 4; r++)                                          \
            MVL[t * 4 + r] = mbase[(size_t)(t * 16 + r) * 2048 + ((KT) + 1) * 32]; \
      }                                                                        \
      asm volatile("" ::: "memory");  /* mask group BEFORE K group in queue */ \
      if ((KT) + 1 < 64) {                                                     \
        const unsigned short* kg = kgb + (size_t)((KT) + 1) * 16384;           \
        unsigned short* kd = &Kbuf[((KT) + 1) & 1][0];                         \
        _Pragma("unroll")                                                      \
        for (int i = 0; i < 16; i++) {                                         \
          int r = (w << 4) + i;                                                \
          gld16(kg + (size_t)r * 512 + ((lane ^ (r & 7)) * 8), kd + r * 512);  \
        }                                                                      \
      }                                                                        \
      /* retire K(KT) (and mask(KT)); leave next window in flight */           \
      if ((KT) < 63) asm volatile("s_waitcnt vmcnt(24)" ::: "memory");         \
      else           asm volatile("s_waitcnt vmcnt(0)"  ::: "memory");         \
    }                                                                          \
    asm volatile("s_barrier" ::: "memory"); /* K(KT) resident for all waves */ \
    if (isS) {                                                                 \
      /* S(KT): 32 rows x 16 keys */                                           \
      const unsigned short* Kc = &Kbuf[(KT) & 1][0];                           \
      f32x4 c0a = (f32x4){0.f,0.f,0.f,0.f}, c1a = (f32x4){0.f,0.f,0.f,0.f};    \
      f32x4 c0b = (f32x4){0.f,0.f,0.f,0.f}, c1b = (f32x4){0.f,0.f,0.f,0.f};    \
      __builtin_amdgcn_s_setprio(1);                                           \
      _Pragma("unroll")                                                        \
      for (int ks = 0; ks < 16; ks += 2) {                                     \
        int o = (ks >> 1) * 64;                                                \
        s16x8 bE = *(const s16x8*)&Kc[krow + o + oE];                          \
        c0a = mfma16(__builtin_bit_cast(s16x8, st[ks]), bE, c0a);              \
        c0b = mfma16(__builtin_bit_cast(s16x8, st[16 + ks]), bE, c0b);         \
        s16x8 bO = *(const s16x8*)&Kc[krow + o + oO];                          \
        c1a = mfma16(__builtin_bit_cast(s16x8, st[ks + 1]), bO, c1a);          \
        c1b = mfma16(__builtin_bit_cast(s16x8, st[16 + ks + 1]), bO, c1b);     \
      }                                                                        \
      __builtin_amdgcn_s_setprio(0);                                           \
      f32x4 sA = c0a + c1a;                                                    \
      f32x4 sB = c0b + c1b;                                                    \
      _Pragma("unroll")                                                        \
      for (int r = 0; r < 4; r++) {                                            \
        float p0 = __expf(sA[r] * (SCALE * MVU[r]));                           \
        float p1 = __expf(sB[r] * (SCALE * MVU[4 + r]));                       \
        lsum[r] += p0; lsum[4 + r] += p1;                                      \
        Pbuf[cur][(quad * 4 + r) * 36 + ksw * 16 + m]      = f2bf(p0);         \
        Pbuf[cur][(16 + quad * 4 + r) * 36 + ksw * 16 + m] = f2bf(p1);         \
      }                                                                        \
      asm volatile("s_waitcnt lgkmcnt(0)" ::: "memory");                       \
    } else {                                                                   \
      if ((KT) > 0) {                                                          \
        /* PV(KT-1): 32 rows x 256 cols, V in regs (vf = V(KT-1)) */           \
        const unsigned short* Pc = &Pbuf[cur ^ 1][0];                          \
        s16x8 pf0 = *(const s16x8*)&Pc[(0 * 16 + m) * 36 + quad * 8];          \
        s16x8 pf1 = *(const s16x8*)&Pc[(1 * 16 + m) * 36 + quad * 8];          \
        __builtin_amdgcn_s_setprio(1);                                         \
        _Pragma("unroll")                                                      \
        for (int dt = 0; dt < 16; dt++) {                                      \
          st[dt]      = mfma16(pf0, vf[dt], st[dt]);                           \
          st[16 + dt] = mfma16(pf1, vf[dt], st[16 + dt]);                      \
        }                                                                      \
        __builtin_amdgcn_s_setprio(0);                                         \
      }                                                                        \
      /* issue vf <- V(KT) now; drained by auto-waitcnt at next-iter use */    \
      _Pragma("unroll")                                                        \
      for (int dt = 0; dt < 16; dt++)                                          \
        vf[dt] = *(const s16x8*)(vlane + (size_t)(KT) * 16384 + dt * 512);     \
    }                                                                          \
  }

  #pragma unroll 1
  for (int kt2 = 0; kt2 < 64; kt2 += 2) {
    FLASH_ITER(kt2,     mvA, mvB)
    FLASH_ITER(kt2 + 1, mvB, mvA)
  }
#undef FLASH_ITER

  // ---- epilogue: PV(63) + lsum exchange + normalize + store ----
  asm volatile("s_waitcnt vmcnt(0)" ::: "memory");   // V(63) resident (PV)
  asm volatile("s_barrier" ::: "memory");            // P(63) visible

  if (!isS) {
    const unsigned short* Pc = &Pbuf[1][0];
    s16x8 pf0 = *(const s16x8*)&Pc[(0 * 16 + m) * 36 + quad * 8];
    s16x8 pf1 = *(const s16x8*)&Pc[(1 * 16 + m) * 36 + quad * 8];
    #pragma unroll
    for (int dt = 0; dt < 16; dt++) {
      st[dt]      = mfma16(pf0, vf[dt], st[dt]);
      st[16 + dt] = mfma16(pf1, vf[dt], st[16 + dt]);
    }
  } else {
    #pragma unroll
    for (int i = 0; i < 8; i++) {
      float t = lsum[i];
      t += __shfl_xor(t, 1);
      t += __shfl_xor(t, 2);
      t += __shfl_xor(t, 4);
      t += __shfl_xor(t, 8);
      lsum[i] = t;
    }
    if (m == 0) {
      #pragma unroll
      for (int t = 0; t < 2; t++)
        #pragma unroll
        for (int r = 0; r < 4; r++)
          LSf[ksw][t * 16 + quad * 4 + r] = lsum[t * 4 + r];
    }
    asm volatile("s_waitcnt lgkmcnt(0)" ::: "memory");
  }
  asm volatile("s_barrier" ::: "memory");

  if (!isS) {
    #pragma unroll
    for (int t = 0; t < 2; t++) {
      #pragma unroll
      for (int r = 0; r < 4; r++) {
        int row = t * 16 + quad * 4 + r;
        float linv = 1.0f / (LSf[0][row] + LSf[1][row]);
        float* orow = out + ((size_t)b * 2048 + q0 + row) * 512 + dq * 256 + m;
        #pragma unroll
        for (int dt = 0; dt < 16; dt++)
          orow[dt * 16] = st[t * 16 + dt][r] * linv;
      }
    }
  }
}

// ---------------------------------------------------------------------------
extern "C" void kernel_launch(void* const* d_in, const int* in_sizes, int n_in,
                              void* d_out, int out_size, void* d_ws, size_t ws_size,
                              hipStream_t stream)
{
  const float* q    = (const float*)d_in[0];
  const float* k    = (const float*)d_in[1];
  const float* v    = (const float*)d_in[2];
  const float* Wq   = (const float*)d_in[3];
  const float* bq   = (const float*)d_in[4];
  const float* Wk   = (const float*)d_in[5];
  const float* bk   = (const float*)d_in[6];
  const float* Wv   = (const float*)d_in[7];
  const float* bv   = (const float*)d_in[8];
  const float* mask = (const float*)d_in[9];
  float* out = (float*)d_out;

  unsigned short* qp  = (unsigned short*)d_ws;
  unsigned short* kp  = qp + (size_t)16384 * 512;
  unsigned short* vpT = kp + (size_t)16384 * 512;

  proj_kernel<<<dim3(1536, 1, 1), dim3(256, 1, 1), 0, stream>>>(
      q, k, v, Wq, bq, Wk, bk, Wv, bv, qp, kp, vpT);
  flash_kernel<<<dim3(512, 1, 1), dim3(256, 1, 1), 0, stream>>>(
      qp, kp, vpT, mask, out);
}

// Round 6
// 395.897 us; speedup vs baseline: 1.6633x; 1.6633x over previous
//
#include <hip/hip_runtime.h>
#include <hip/hip_bf16.h>

// ---------------------------------------------------------------------------
// Attention: out = softmax((q Wq^T + bq)(k Wk^T + bk)^T * inv_sqrt_d * mask) (v Wv^T + bv)
// B=8, T=2048, D=512.  fp32 I/O; bf16 MFMA, fp32 accum.
//
// ws layout (50,331,648 B, all LINEAR — swizzles live in DMA source addresses):
//   qp  [16384][512] bf16
//   kp  [16384][512] bf16
//   vpT [b][kt=64][d=512][32] bf16
// ---------------------------------------------------------------------------

typedef __attribute__((ext_vector_type(4))) float  f32x4;
typedef __attribute__((ext_vector_type(8))) short  s16x8;
typedef __attribute__((ext_vector_type(8))) __bf16 bf16x8;

#define AS1 __attribute__((address_space(1)))
#define AS3 __attribute__((address_space(3)))

__device__ __forceinline__ f32x4 mfma16(s16x8 a, s16x8 b, f32x4 c) {
  return __builtin_amdgcn_mfma_f32_16x16x32_bf16(
      __builtin_bit_cast(bf16x8, a), __builtin_bit_cast(bf16x8, b), c, 0, 0, 0);
}

__device__ __forceinline__ unsigned short f2bf(float f) {
  unsigned u = __float_as_uint(f);
  return (unsigned short)((u + 0x7fffu + ((u >> 16) & 1u)) >> 16);
}

__device__ __forceinline__ s16x8 pack8(f32x4 a, f32x4 b) {
  union { s16x8 v; unsigned int u[4]; } r;
  __hip_bfloat162 t0 = __float22bfloat162_rn(make_float2(a[0], a[1]));
  __hip_bfloat162 t1 = __float22bfloat162_rn(make_float2(a[2], a[3]));
  __hip_bfloat162 t2 = __float22bfloat162_rn(make_float2(b[0], b[1]));
  __hip_bfloat162 t3 = __float22bfloat162_rn(make_float2(b[2], b[3]));
  __builtin_memcpy(&r.u[0], &t0, 4);
  __builtin_memcpy(&r.u[1], &t1, 4);
  __builtin_memcpy(&r.u[2], &t2, 4);
  __builtin_memcpy(&r.u[3], &t3, 4);
  return r.v;
}

__device__ __forceinline__ void gld16(const unsigned short* g, unsigned short* l) {
  __builtin_amdgcn_global_load_lds((const AS1 unsigned int*)g,
                                   (AS3 unsigned int*)l, 16, 0, 0);
}
__device__ __forceinline__ void gldf(const float* g, float* l) {
  __builtin_amdgcn_global_load_lds((const AS1 unsigned int*)g,
                                   (AS3 unsigned int*)l, 16, 0, 0);
}

#define SCALE 0.044194173824159216f  // 1/sqrt(512)

// ---------------------------------------------------------------------------
// Projection GEMM (unchanged).
// ---------------------------------------------------------------------------
__global__ __launch_bounds__(256, 2) void proj_kernel(
    const float* __restrict__ q,  const float* __restrict__ kk, const float* __restrict__ v,
    const float* __restrict__ Wq, const float* __restrict__ bq,
    const float* __restrict__ Wk, const float* __restrict__ bk,
    const float* __restrict__ Wv, const float* __restrict__ bv,
    unsigned short* __restrict__ qp, unsigned short* __restrict__ kp,
    unsigned short* __restrict__ vpT)
{
  const int id = blockIdx.x;
  const int c  = id & 7;
  const int j  = id >> 3;
  const int z  = j >> 6;
  const int j2 = j & 63;
  int xt, yt;
  if (z < 2) { yt = j2 & 3; xt = (j2 >> 2) * 8 + c; }
  else       { xt = j2 & 3; yt = (j2 >> 2) * 8 + c; }

  const float* Asrc; const float* Bsrc; const float* bias;
  if (z == 0)      { Asrc = q;  Bsrc = Wq; bias = bq; }
  else if (z == 1) { Asrc = kk; Bsrc = Wk; bias = bk; }
  else             { Asrc = Wv; Bsrc = v;  bias = bv; }
  const int Arow0 = xt * 128, Brow0 = yt * 128;
  const float* Ag = Asrc + (size_t)Arow0 * 512;
  const float* Bg = Bsrc + (size_t)Brow0 * 512;

  __shared__ __align__(16) float Abuf[2][128 * 32];
  __shared__ __align__(16) float Bbuf[2][128 * 32];

  const int tid  = threadIdx.x;
  const int lane = tid & 63;
  const int w    = tid >> 6;
  const int wr   = w >> 1, wc = w & 1;
  const int m    = lane & 15;
  const int quad = lane >> 4;

  const int lr = lane >> 3;
  const int sw = ((lane & 7) ^ lr) * 4;

  f32x4 acc[4][4];
  #pragma unroll
  for (int i = 0; i < 4; i++)
    #pragma unroll
    for (int n = 0; n < 4; n++) acc[i][n] = (f32x4){0.f, 0.f, 0.f, 0.f};

  #pragma unroll
  for (int i = 0; i < 4; i++) {
    int r0 = w * 32 + i * 8;
    gldf(Ag + (size_t)(r0 + lr) * 512 + sw, &Abuf[0][r0 * 32]);
  }
  #pragma unroll
  for (int i = 0; i < 4; i++) {
    int r0 = w * 32 + i * 8;
    gldf(Bg + (size_t)(r0 + lr) * 512 + sw, &Bbuf[0][r0 * 32]);
  }

  const int xrow = m & 7;

  #pragma unroll 1
  for (int kc = 0; kc < 16; kc++) {
    const int cur = kc & 1;
    asm volatile("s_barrier" ::: "memory");
    if (kc < 15) {
      const int nxt = cur ^ 1;
      const size_t ko = (size_t)(kc + 1) * 32;
      #pragma unroll
      for (int i = 0; i < 4; i++) {
        int r0 = w * 32 + i * 8;
        gldf(Ag + (size_t)(r0 + lr) * 512 + ko + sw, &Abuf[nxt][r0 * 32]);
      }
      #pragma unroll
      for (int i = 0; i < 4; i++) {
        int r0 = w * 32 + i * 8;
        gldf(Bg + (size_t)(r0 + lr) * 512 + ko + sw, &Bbuf[nxt][r0 * 32]);
      }
      asm volatile("s_waitcnt vmcnt(8)" ::: "memory");
    } else {
      asm volatile("s_waitcnt vmcnt(0)" ::: "memory");
    }
    asm volatile("s_barrier" ::: "memory");

    const float* Ac = &Abuf[cur][0];
    const float* Bc = &Bbuf[cur][0];
    s16x8 af[4], bf[4];
    #pragma unroll
    for (int mt = 0; mt < 4; mt++) {
      int row = wr * 64 + mt * 16 + m;
      int p0 = ((quad * 2) ^ xrow) * 4, p1 = ((quad * 2 + 1) ^ xrow) * 4;
      f32x4 a = *(const f32x4*)(Ac + row * 32 + p0);
      f32x4 b = *(const f32x4*)(Ac + row * 32 + p1);
      af[mt] = pack8(a, b);
    }
    #pragma unroll
    for (int nt = 0; nt < 4; nt++) {
      int row = wc * 64 + nt * 16 + m;
      int p0 = ((quad * 2) ^ xrow) * 4, p1 = ((quad * 2 + 1) ^ xrow) * 4;
      f32x4 a = *(const f32x4*)(Bc + row * 32 + p0);
      f32x4 b = *(const f32x4*)(Bc + row * 32 + p1);
      bf[nt] = pack8(a, b);
    }
    #pragma unroll
    for (int mt = 0; mt < 4; mt++)
      #pragma unroll
      for (int nt = 0; nt < 4; nt++)
        acc[mt][nt] = mfma16(af[mt], bf[nt], acc[mt][nt]);
  }

  if (z < 2) {
    unsigned short* o = (z == 0) ? qp : kp;
    #pragma unroll
    for (int nt = 0; nt < 4; nt++) {
      int   e_g = Brow0 + wc * 64 + nt * 16 + m;
      float bb  = bias[e_g];
      #pragma unroll
      for (int mt = 0; mt < 4; mt++) {
        #pragma unroll
        for (int r = 0; r < 4; r++) {
          int t_g = Arow0 + wr * 64 + mt * 16 + quad * 4 + r;
          o[(size_t)t_g * 512 + e_g] = f2bf(acc[mt][nt][r] + bb);
        }
      }
    }
  } else {
    #pragma unroll
    for (int mt = 0; mt < 4; mt++) {
      #pragma unroll
      for (int r = 0; r < 4; r++) {
        int   e_g = Arow0 + wr * 64 + mt * 16 + quad * 4 + r;
        float bb  = bias[e_g];
        #pragma unroll
        for (int nt = 0; nt < 4; nt++) {
          int t_g = Brow0 + wc * 64 + nt * 16 + m;
          int bbi = t_g >> 11, ti = t_g & 2047;
          int ktl = ti >> 5,   kq = ti & 31;
          vpT[(((size_t)bbi * 64 + ktl) * 512 + e_g) * 32 + kq] =
              f2bf(acc[mt][nt][r] + bb);
        }
      }
    }
  }
}

// ---------------------------------------------------------------------------
// Flash attention v7 = v5 (verified 131 us) + loosened drain.
// 512 thr = 8 waves, 64 q-rows/block, BK=32, grid 256 (b=id&7 -> one batch/XCD).
// S-waves (w<4): 32 rows x 16 keys; stage ALL K (8 gld/iter) + mask (8 loads).
//   Issue order per iter: mask(KT+1) | K(KT+2).
//   Drain vmcnt(48): retires ONLY K(KT) (queue algebra: after retiring K(KT),
//   exactly [mask(KT)8, K(KT+1)16, mask(KT+1)8, K(KT+2)16] = 48 remain).
//   mask(KT) wait auto-sinks to the compiler waitcnt at first MVU use — AFTER
//   the 32 MFMAs — so mask latency overlaps compute instead of the barrier.
// PV-waves (w>=4): dq=w&3 d-quarter, lag 1 iter; V direct global->reg vf[8].
// Kbuf[4] ring 128 KB, Pbuf parity-dbuf 9 KB. 2 barriers/iter. Regs: 128 VGPR
// + 128 AGPR = 256/wave (8 waves/CU cap — do NOT add registers).
// ---------------------------------------------------------------------------
__global__ __launch_bounds__(512, 2) void flash_kernel(
    const unsigned short* __restrict__ qp, const unsigned short* __restrict__ kp,
    const unsigned short* __restrict__ vpT, const float* __restrict__ mask,
    float* __restrict__ out)
{
  const int id   = blockIdx.x;
  const int b    = id & 7;
  const int q0   = (id >> 3) * 64;
  const int tid  = threadIdx.x;
  const int lane = tid & 63;
  const int w    = tid >> 6;
  const int m    = lane & 15;
  const int quad = lane >> 4;
  const bool isS = (w < 4);
  const int rsw  = w & 1;          // S: row-half (32 rows)
  const int ksw  = (w >> 1) & 1;   // S: key-half (16 keys)
  const int dq   = w & 3;          // PV: d-quarter (128 cols)

  __shared__ __align__(16) unsigned short Kbuf[4][32 * 512];  // 128 KB ring
  __shared__ __align__(16) unsigned short Pbuf[2][64 * 36];   // 9 KB
  __shared__ float LSf[2][64];

  const unsigned short* kgb   = kp  + (size_t)b * 2048 * 512;
  // per-lane V base: e=(dq*128+m), kq=quad*8 ; +dt*512 shorts per d-subtile,
  // +16384 shorts per key-tile. 16B/lane, wave covers a contiguous 1 KB block.
  const unsigned short* vlane = vpT + (size_t)b * 64 * 16384
                              + (size_t)(dq * 128 + m) * 32 + quad * 8;
  const float* mbase = mask + ((size_t)b * 2048 + q0 + rsw * 32 + quad * 4) * 2048
                     + ksw * 16 + m;

  // swizzled K-read offsets (conflict-verified family)
  const int oE   = ((quad ^ (m & 7)) & 7) * 8;
  const int oO   = (((quad ^ (m & 7)) ^ 4) & 7) * 8;
  const int krow = (ksw * 16 + m) * 512;

  f32x4 st[32];              // S-waves: Q frags (bit-cast) | PV-waves: O acc
  s16x8 vf[8];               // PV-waves: V frags for current lagged tile
  float lsum[8] = {0.f, 0.f, 0.f, 0.f, 0.f, 0.f, 0.f, 0.f};
  float mvA[8], mvB[8];

  if (isS) {
    const unsigned short* qb = qp + ((size_t)b * 2048 + q0 + rsw * 32 + m) * 512;
    #pragma unroll
    for (int ks = 0; ks < 16; ks++) {
      s16x8 a0 = *(const s16x8*)(qb + ks * 32 + quad * 8);
      s16x8 a1 = *(const s16x8*)(qb + 16 * 512 + ks * 32 + quad * 8);
      st[ks]      = __builtin_bit_cast(f32x4, a0);
      st[16 + ks] = __builtin_bit_cast(f32x4, a1);
    }
    asm volatile("" ::: "memory");      // keep VMEM issue groups ordered
    // mask(0)
    #pragma unroll
    for (int t = 0; t < 2; t++)
      #pragma unroll
      for (int r = 0; r < 4; r++)
        mvA[t * 4 + r] = mbase[(size_t)(t * 16 + r) * 2048];
    asm volatile("" ::: "memory");
    // K(0)
    #pragma unroll
    for (int i = 0; i < 8; i++) {
      int r = (w << 3) + i;
      gld16(kgb + (size_t)r * 512 + ((lane ^ (r & 7)) * 8), &Kbuf[0][r * 512]);
    }
    asm volatile("" ::: "memory");
    // K(1)
    #pragma unroll
    for (int i = 0; i < 8; i++) {
      int r = (w << 3) + i;
      gld16(kgb + 16384 + (size_t)r * 512 + ((lane ^ (r & 7)) * 8),
            &Kbuf[1][r * 512]);
    }
  } else {
    #pragma unroll
    for (int i = 0; i < 32; i++) st[i] = (f32x4){0.f, 0.f, 0.f, 0.f};
  }
  asm volatile("s_waitcnt vmcnt(0)" ::: "memory");  // Q, K(0), mask(0) resident

// Per-wave VMEM queues (oldest -> newest), in-order retirement:
//   S : ..., mask(KT), K(KT+1), mask(KT+1), K(KT+2)  (24 issued/iter)
//       vmcnt(48) at iter KT retires exactly through K(KT); mask(KT) is
//       auto-waited by the compiler at its first use (after the MFMA block).
//   PV: [vf = V(KT-1)] only -> compiler auto-wait before first MFMA use.
#define FLASH_ITER(KT, MVU, MVL)                                               \
  {                                                                            \
    const int cur = (KT) & 1;                                                  \
    asm volatile("s_barrier" ::: "memory"); /* compute(KT-1) done all waves */ \
    if (isS) {                                                                 \
      if ((KT) + 1 < 64) {                                                     \
        _Pragma("unroll")                                                      \
        for (int t = 0; t < 2; t++)                                            \
          _Pragma("unroll")                                                    \
          for (int r = 0; r < 4; r++)                                          \
            MVL[t * 4 + r] = mbase[(size_t)(t * 16 + r) * 2048 + ((KT) + 1) * 32]; \
      }                                                                        \
      asm volatile("" ::: "memory");  /* mask group BEFORE K group in queue */ \
      if ((KT) + 2 < 64) {                                                     \
        const unsigned short* kg = kgb + (size_t)((KT) + 2) * 16384;           \
        unsigned short* kd = &Kbuf[((KT) + 2) & 3][0];                         \
        _Pragma("unroll")                                                      \
        for (int i = 0; i < 8; i++) {                                          \
          int r = (w << 3) + i;                                                \
          gld16(kg + (size_t)r * 512 + ((lane ^ (r & 7)) * 8), kd + r * 512);  \
        }                                                                      \
      }                                                                        \
      /* retire ONLY K(KT); mask(KT) wait sinks into the compute phase */      \
      if ((KT) < 62)       asm volatile("s_waitcnt vmcnt(48)" ::: "memory");   \
      else if ((KT) == 62) asm volatile("s_waitcnt vmcnt(32)" ::: "memory");   \
      else                 asm volatile("s_waitcnt vmcnt(8)"  ::: "memory");   \
    }                                                                          \
    asm volatile("s_barrier" ::: "memory"); /* K(KT) resident for all waves */ \
    if (isS) {                                                                 \
      /* S(KT): 32 rows x 16 keys; K frags shared across row-tiles */          \
      const unsigned short* Kc = &Kbuf[(KT) & 3][0];                           \
      f32x4 c0a = (f32x4){0.f,0.f,0.f,0.f}, c1a = (f32x4){0.f,0.f,0.f,0.f};    \
      f32x4 c0b = (f32x4){0.f,0.f,0.f,0.f}, c1b = (f32x4){0.f,0.f,0.f,0.f};    \
      __builtin_amdgcn_s_setprio(1);                                           \
      _Pragma("unroll")                                                        \
      for (int ks = 0; ks < 16; ks += 2) {                                     \
        int o = (ks >> 1) * 64;                                                \
        s16x8 bE = *(const s16x8*)&Kc[krow + o + oE];                          \
        c0a = mfma16(__builtin_bit_cast(s16x8, st[ks]), bE, c0a);              \
        c0b = mfma16(__builtin_bit_cast(s16x8, st[16 + ks]), bE, c0b);         \
        s16x8 bO = *(const s16x8*)&Kc[krow + o + oO];                          \
        c1a = mfma16(__builtin_bit_cast(s16x8, st[ks + 1]), bO, c1a);          \
        c1b = mfma16(__builtin_bit_cast(s16x8, st[16 + ks + 1]), bO, c1b);     \
      }                                                                        \
      __builtin_amdgcn_s_setprio(0);                                           \
      f32x4 sA = c0a + c1a;                                                    \
      f32x4 sB = c0b + c1b;                                                    \
      _Pragma("unroll")                                                        \
      for (int r = 0; r < 4; r++) {                                            \
        float p0 = __expf(sA[r] * (SCALE * MVU[r]));                           \
        float p1 = __expf(sB[r] * (SCALE * MVU[4 + r]));                       \
        lsum[r] += p0; lsum[4 + r] += p1;                                      \
        Pbuf[cur][(rsw * 32 + quad * 4 + r) * 36 + ksw * 16 + m]      = f2bf(p0); \
        Pbuf[cur][(rsw * 32 + 16 + quad * 4 + r) * 36 + ksw * 16 + m] = f2bf(p1); \
      }                                                                        \
      asm volatile("s_waitcnt lgkmcnt(0)" ::: "memory");                       \
    } else {                                                                   \
      if ((KT) > 0) {                                                          \
        /* PV(KT-1): all 64 rows x 128 cols, V in regs (vf = V(KT-1)) */       \
        const unsigned short* Pc = &Pbuf[cur ^ 1][0];                          \
        s16x8 pf0 = *(const s16x8*)&Pc[(0 * 16 + m) * 36 + quad * 8];          \
        s16x8 pf1 = *(const s16x8*)&Pc[(1 * 16 + m) * 36 + quad * 8];          \
        s16x8 pf2 = *(const s16x8*)&Pc[(2 * 16 + m) * 36 + quad * 8];          \
        s16x8 pf3 = *(const s16x8*)&Pc[(3 * 16 + m) * 36 + quad * 8];          \
        __builtin_amdgcn_s_setprio(1);                                         \
        _Pragma("unroll")                                                      \
        for (int dt = 0; dt < 8; dt++) {                                       \
          st[dt]      = mfma16(pf0, vf[dt], st[dt]);                           \
          st[8 + dt]  = mfma16(pf1, vf[dt], st[8 + dt]);                       \
          st[16 + dt] = mfma16(pf2, vf[dt], st[16 + dt]);                      \
          st[24 + dt] = mfma16(pf3, vf[dt], st[24 + dt]);                      \
        }                                                                      \
        __builtin_amdgcn_s_setprio(0);                                         \
      }                                                                        \
      /* issue vf <- V(KT) now; drained by auto-waitcnt at next-iter use */    \
      _Pragma("unroll")                                                        \
      for (int dt = 0; dt < 8; dt++)                                           \
        vf[dt] = *(const s16x8*)(vlane + (size_t)(KT) * 16384 + dt * 512);     \
    }                                                                          \
  }

  #pragma unroll 1
  for (int kt2 = 0; kt2 < 64; kt2 += 2) {
    FLASH_ITER(kt2,     mvA, mvB)
    FLASH_ITER(kt2 + 1, mvB, mvA)
  }
#undef FLASH_ITER

  // ---- epilogue: PV(63) + lsum exchange + normalize + store ----
  asm volatile("s_waitcnt vmcnt(0)" ::: "memory");   // V(63) resident (PV)
  asm volatile("s_barrier" ::: "memory");            // P(63) visible

  if (!isS) {
    const unsigned short* Pc = &Pbuf[1][0];
    s16x8 pf0 = *(const s16x8*)&Pc[(0 * 16 + m) * 36 + quad * 8];
    s16x8 pf1 = *(const s16x8*)&Pc[(1 * 16 + m) * 36 + quad * 8];
    s16x8 pf2 = *(const s16x8*)&Pc[(2 * 16 + m) * 36 + quad * 8];
    s16x8 pf3 = *(const s16x8*)&Pc[(3 * 16 + m) * 36 + quad * 8];
    #pragma unroll
    for (int dt = 0; dt < 8; dt++) {
      s16x8 vfx = vf[dt];
      st[dt]      = mfma16(pf0, vfx, st[dt]);
      st[8 + dt]  = mfma16(pf1, vfx, st[8 + dt]);
      st[16 + dt] = mfma16(pf2, vfx, st[16 + dt]);
      st[24 + dt] = mfma16(pf3, vfx, st[24 + dt]);
    }
  } else {
    #pragma unroll
    for (int i = 0; i < 8; i++) {
      float t = lsum[i];
      t += __shfl_xor(t, 1);
      t += __shfl_xor(t, 2);
      t += __shfl_xor(t, 4);
      t += __shfl_xor(t, 8);
      lsum[i] = t;
    }
    if (m == 0) {
      #pragma unroll
      for (int t = 0; t < 2; t++)
        #pragma unroll
        for (int r = 0; r < 4; r++)
          LSf[ksw][rsw * 32 + t * 16 + quad * 4 + r] = lsum[t * 4 + r];
    }
    asm volatile("s_waitcnt lgkmcnt(0)" ::: "memory");
  }
  asm volatile("s_barrier" ::: "memory");

  if (!isS) {
    #pragma unroll
    for (int t = 0; t < 4; t++) {
      #pragma unroll
      for (int r = 0; r < 4; r++) {
        int row = t * 16 + quad * 4 + r;
        float linv = 1.0f / (LSf[0][row] + LSf[1][row]);
        float* orow = out + ((size_t)b * 2048 + q0 + row) * 512 + dq * 128 + m;
        #pragma unroll
        for (int dt = 0; dt < 8; dt++)
          orow[dt * 16] = st[t * 8 + dt][r] * linv;
      }
    }
  }
}

// ---------------------------------------------------------------------------
extern "C" void kernel_launch(void* const* d_in, const int* in_sizes, int n_in,
                              void* d_out, int out_size, void* d_ws, size_t ws_size,
                              hipStream_t stream)
{
  const float* q    = (const float*)d_in[0];
  const float* k    = (const float*)d_in[1];
  const float* v    = (const float*)d_in[2];
  const float* Wq   = (const float*)d_in[3];
  const float* bq   = (const float*)d_in[4];
  const float* Wk   = (const float*)d_in[5];
  const float* bk   = (const float*)d_in[6];
  const float* Wv   = (const float*)d_in[7];
  const float* bv   = (const float*)d_in[8];
  const float* mask = (const float*)d_in[9];
  float* out = (float*)d_out;

  unsigned short* qp  = (unsigned short*)d_ws;
  unsigned short* kp  = qp + (size_t)16384 * 512;
  unsigned short* vpT = kp + (size_t)16384 * 512;

  proj_kernel<<<dim3(1536, 1, 1), dim3(256, 1, 1), 0, stream>>>(
      q, k, v, Wq, bq, Wk, bk, Wv, bv, qp, kp, vpT);
  flash_kernel<<<dim3(256, 1, 1), dim3(512, 1, 1), 0, stream>>>(
      qp, kp, vpT, mask, out);
}